// Round 4
// baseline (106.462 us; speedup 1.0000x reference)
//
#include <hip/hip_runtime.h>
#include <hip/hip_bf16.h>

// Renderer interpolation: out[p, d] = sum_k bary[p,k] * attributes[faces[wrap(pix[p])][k], d]
// mask[p] = (pix[p] != -1)
// H=W=1024, D=32, F=100000, V=50000.
//
// XCD d-split: each block covers ONE 64-byte half of the attribute rows
// (h = blockIdx.x & 1). Workgroup dispatch round-robins bid%8 across the 8
// XCDs, so every XCD only gathers one half of the 6.4MB attributes table:
// per-XCD working set = 50000 * 64B = 3.2MB < 4MB L2 -> gathers become L2
// hits instead of L3/HBM misses (latency*concurrency bound -> lower latency
// -> higher gather throughput).
//
// Layout: 4 threads per (pixel, half). Lane q in [0,4) of a pixel handles
// float4 chunk t = 4h + q, so each pixel's 4 lanes read a contiguous,
// 64B-aligned half-line from the attributes table (fully coalesced), and
// the float4 output stores are 64B-contiguous per pixel group.

typedef float fvec4 __attribute__((ext_vector_type(4)));

__global__ __launch_bounds__(256) void Renderer_interp_kernel(
    const int* __restrict__ pix,      // (npix)
    const float* __restrict__ bary,   // (npix, 3)
    const int* __restrict__ faces,    // (F, 3)
    const float* __restrict__ attr,   // (V, 32)
    float* __restrict__ out,          // (npix, 32)
    float* __restrict__ mask,         // (npix) as float 0/1
    int npix, int F)
{
    // block: 256 threads = 64 pixels x 4 lanes, one half-row (h) per block
    int h    = blockIdx.x & 1;          // which 64B half of the attr row
    int pblk = blockIdx.x >> 1;         // pixel-block index
    int lp   = threadIdx.x >> 2;        // local pixel 0..63
    int q    = threadIdx.x & 3;         // float4 chunk within half
    int p    = pblk * 64 + lp;
    if (p >= npix) return;

    int t = h * 4 + q;                  // float4 chunk within full row (0..7)

    // ---- stage 1: pixel->face (streaming) ----
    int fraw = __builtin_nontemporal_load(&pix[p]);
    int f = (fraw < 0) ? (fraw + F) : fraw;   // mode='wrap': -1 -> F-1

    // ---- stage 2: face->vertices (1.2MB table, cached) ----
    int base = 3 * f;
    int v0 = faces[base + 0];
    int v1 = faces[base + 1];
    int v2 = faces[base + 2];

    float w0 = __builtin_nontemporal_load(&bary[3 * p + 0]);
    float w1 = __builtin_nontemporal_load(&bary[3 * p + 1]);
    float w2 = __builtin_nontemporal_load(&bary[3 * p + 2]);

    // ---- stage 3: vertex->attributes (this XCD's 3.2MB half, L2-resident) ----
    const fvec4* A = reinterpret_cast<const fvec4*>(attr);
    fvec4 r0 = A[v0 * 8 + t];
    fvec4 r1 = A[v1 * 8 + t];
    fvec4 r2 = A[v2 * 8 + t];

    fvec4 o = w0 * r0 + w1 * r1 + w2 * r2;

    // ---- output (streaming) ----
    fvec4* O = reinterpret_cast<fvec4*>(out);
    __builtin_nontemporal_store(o, &O[(size_t)p * 8 + t]);

    if (h == 0 && q == 0) {
        __builtin_nontemporal_store((fraw != -1) ? 1.0f : 0.0f, &mask[p]);
    }
}

extern "C" void kernel_launch(void* const* d_in, const int* in_sizes, int n_in,
                              void* d_out, int out_size, void* d_ws, size_t ws_size,
                              hipStream_t stream) {
    const int*   pix   = (const int*)d_in[0];
    const float* bary  = (const float*)d_in[1];
    const int*   faces = (const int*)d_in[2];
    const float* attr  = (const float*)d_in[3];

    int npix = in_sizes[0];        // H*W = 1048576
    int F    = in_sizes[2] / 3;    // 100000

    float* out  = (float*)d_out;                      // (npix, 32)
    float* mask = (float*)d_out + (size_t)npix * 32;  // (npix,)

    // 64 pixels per block, 2 half-blocks per 64 pixels
    int nblk = ((npix + 63) / 64) * 2;
    Renderer_interp_kernel<<<nblk, 256, 0, stream>>>(pix, bary, faces, attr,
                                                     out, mask, npix, F);
}